// Round 4
// baseline (133.785 us; speedup 1.0000x reference)
//
#include <hip/hip_runtime.h>

// EfficientPairEmbed: out[0, e, h] = sum_g emb[anum[src_e], anum[dst_e], 0, h, g] * rbf[e, g]
// rbf[e,g] = exp(-0.5/std^2 * (dist_e - offset_g)^2), offsets = linspace(0, 12, 50), std = 12/50.
//
// R9b: compile fix only (nontemporal builtin needs a native vector type, not
// HIP_vector_type). Theory unchanged from R9:
// R7 (coalesced requests) and R8 (aligned 1-line windows) were BOTH null =>
// gather is bound by L2-MISS traffic (random 128B lines served by L3 at ~2-3 TB/s).
// Arithmetic: R6 240MB requests @ ~50% L2 hit = 120MB miss; R8 128MB @ ~7% = 119MB
// miss -- identical, hence identical time. Fix: temporal slicing. Gather runs twice;
// pass k touches only pairs in a 4MB half of the 8MB table, so every XCD's random
// fetches hit its own L2 (34.5 TB/s) after a 4MB cold fill. Streams stay nontemporal
// so they don't evict the slice. Numerics bit-identical to R6/R7 (absmax 0.03125).

#define G_NUM 50
#define H_NUM 8
#define NE_NUM 100
#define N_PAIRS (NE_NUM * NE_NUM)
#define WIN 8
#define SLICE_P (N_PAIRS / 2)          // 5000 pairs = 4 MB bf16 slice
#define BLOCK_THREADS 256
#define TP_PAIRS 8                     // pairs per transpose block

#define SPACING (12.0f / (float)(G_NUM - 1))
#define INV_SPACING ((float)(G_NUM - 1) / 12.0f)
#define RBF_COEFF (-0.5f * ((float)G_NUM / 12.0f) * ((float)G_NUM / 12.0f))

typedef float vf4 __attribute__((ext_vector_type(4)));   // native vec for nontemporal stores

__device__ __forceinline__ float bf_lo(unsigned u) { return __uint_as_float(u << 16); }
__device__ __forceinline__ float bf_hi(unsigned u) { return __uint_as_float(u & 0xffff0000u); }

// ---------------- Pass 0: emb [p][h][g] fp32 -> temb [p][g][h] bf16, LDS-staged ----------------
__global__ __launch_bounds__(BLOCK_THREADS) void transpose_cast_kernel(
    const float* __restrict__ emb, unsigned int* __restrict__ temb)
{
    __shared__ float ls[TP_PAIRS * H_NUM * G_NUM];          // 3200 floats, 12.8 KB

    const int tid = threadIdx.x;
    const int p0  = blockIdx.x * TP_PAIRS;

    // Coalesced read: 800 float4 per block.
    const float4* src = (const float4*)(emb + (size_t)p0 * (H_NUM * G_NUM));
    #pragma unroll
    for (int i = tid; i < TP_PAIRS * H_NUM * G_NUM / 4; i += BLOCK_THREADS)
        ((float4*)ls)[i] = src[i];
    __syncthreads();

    // Coalesced write: 1600 packed-bf16 uints per block.
    unsigned int* dst = temb + (size_t)p0 * (H_NUM * G_NUM / 2);
    #pragma unroll
    for (int i = tid; i < TP_PAIRS * H_NUM * G_NUM / 2; i += BLOCK_THREADS) {
        int q  = i / (H_NUM * G_NUM / 2);          // local pair
        int u  = i - q * (H_NUM * G_NUM / 2);      // uint idx within pair: [g][h/2]
        int g  = u >> 2;
        int h0 = (u & 3) * 2;
        float f0 = ls[q * (H_NUM * G_NUM) + h0 * G_NUM + g];
        float f1 = ls[q * (H_NUM * G_NUM) + (h0 + 1) * G_NUM + g];
        unsigned u0 = __float_as_uint(f0);
        unsigned u1 = __float_as_uint(f1);
        unsigned b0 = (u0 + 0x7fffu + ((u0 >> 16) & 1u)) >> 16;   // RNE bf16
        unsigned b1 = (u1 + 0x7fffu + ((u1 >> 16) & 1u)) >> 16;
        dst[i] = (b1 << 16) | (b0 & 0xffffu);
    }
}

// ---------------- Pass 1/2: sliced windowed gather, 1 lane/edge ----------------
// Only edges whose pair falls in [p_lo, p_hi) are processed; the slice's 4MB of
// table is L2-resident on every XCD for the duration of the pass.
__global__ __launch_bounds__(BLOCK_THREADS) void gather_kernel(
    const int* __restrict__ anum,
    const int* __restrict__ edge_index,
    const float* __restrict__ dist,
    const unsigned short* __restrict__ temb,
    float* __restrict__ out,
    int n_edges, int p_lo, int p_hi)
{
    int e = blockIdx.x * BLOCK_THREADS + threadIdx.x;
    if (e >= n_edges) return;

    int s = __builtin_nontemporal_load(edge_index + e);
    int d = __builtin_nontemporal_load(edge_index + n_edges + e);
    int p = anum[s] * NE_NUM + anum[d];
    if (p < p_lo || p >= p_hi) return;          // other slice's pass handles it

    float dv = __builtin_nontemporal_load(dist + e);

    int g0 = (int)(dv * INV_SPACING) - 3;
    if (g0 < 0) g0 = 0;
    if (g0 > G_NUM - WIN) g0 = G_NUM - WIN;

    // Window rows are 16B each ([g][h0..7] bf16), 128B contiguous total.
    const unsigned short* wb = temb + (size_t)p * (H_NUM * G_NUM) + g0 * H_NUM;

    uint4 v[WIN];
    #pragma unroll
    for (int r = 0; r < WIN; ++r)
        v[r] = *(const uint4*)(wb + r * H_NUM);      // 8 independent 16B loads, L2-hit

    float a0 = 0.f, a1 = 0.f, a2 = 0.f, a3 = 0.f;
    float a4 = 0.f, a5 = 0.f, a6 = 0.f, a7 = 0.f;
    #pragma unroll
    for (int r = 0; r < WIN; ++r) {
        float diff = dv - (float)(g0 + r) * SPACING;
        float rb = __expf(RBF_COEFF * diff * diff);
        a0 += rb * bf_lo(v[r].x);
        a1 += rb * bf_hi(v[r].x);
        a2 += rb * bf_lo(v[r].y);
        a3 += rb * bf_hi(v[r].y);
        a4 += rb * bf_lo(v[r].z);
        a5 += rb * bf_hi(v[r].z);
        a6 += rb * bf_lo(v[r].w);
        a7 += rb * bf_hi(v[r].w);
    }

    // Nontemporal: don't let the output stream evict the table slice from L2.
    float* ob = out + (size_t)e * H_NUM;
    vf4 lo = {a0, a1, a2, a3};
    vf4 hi = {a4, a5, a6, a7};
    __builtin_nontemporal_store(lo, (vf4*)ob);
    __builtin_nontemporal_store(hi, (vf4*)(ob + 4));
}

// ---------------- Fallback (ws-free): exact fp32 direct kernel ----------------
__global__ __launch_bounds__(BLOCK_THREADS) void direct_kernel(
    const int* __restrict__ anum,
    const int* __restrict__ edge_index,
    const float* __restrict__ dist,
    const float* __restrict__ emb,
    float* __restrict__ out,
    int n_edges)
{
    __shared__ int   pair_s[32];
    __shared__ float dist_sd[32];
    __shared__ float rbf_sd[32 * G_NUM];

    const int tid = threadIdx.x;
    const int e0  = blockIdx.x * 32;

    if (tid < 32) {
        int e = e0 + tid;
        if (e >= n_edges) e = n_edges - 1;
        int s  = edge_index[e];
        int d  = edge_index[n_edges + e];
        pair_s[tid] = (anum[s] * NE_NUM + anum[d]) * (H_NUM * G_NUM);
        dist_sd[tid] = dist[e];
    }
    __syncthreads();

    for (int idx = tid; idx < 32 * G_NUM; idx += BLOCK_THREADS) {
        int el = idx / G_NUM;
        int g  = idx - el * G_NUM;
        float diff = dist_sd[el] - (float)g * SPACING;
        rbf_sd[idx] = __expf(RBF_COEFF * diff * diff);
    }
    __syncthreads();

    const int el = tid >> 3;
    const int h  = tid & 7;
    const float* ebase = emb + pair_s[el] + h * G_NUM;
    const float* rbase = rbf_sd + el * G_NUM;

    float acc = 0.0f;
    #pragma unroll
    for (int g2 = 0; g2 < G_NUM / 2; ++g2) {
        float2 ev = *(const float2*)(ebase + 2 * g2);
        float2 rv = *(const float2*)(rbase + 2 * g2);
        acc += ev.x * rv.x + ev.y * rv.y;
    }

    if (e0 + el < n_edges)
        out[e0 * H_NUM + tid] = acc;
}

extern "C" void kernel_launch(void* const* d_in, const int* in_sizes, int n_in,
                              void* d_out, int out_size, void* d_ws, size_t ws_size,
                              hipStream_t stream) {
    const int*   anum       = (const int*)d_in[0];
    const int*   edge_index = (const int*)d_in[1];
    const float* dist       = (const float*)d_in[2];
    const float* emb        = (const float*)d_in[3];
    float*       out        = (float*)d_out;
    const int n_edges = in_sizes[2];

    const size_t temb_bytes = (size_t)N_PAIRS * H_NUM * G_NUM * sizeof(unsigned short); // 8 MB

    if (ws_size < temb_bytes) {
        const int grid = (n_edges + 31) / 32;
        direct_kernel<<<grid, BLOCK_THREADS, 0, stream>>>(
            anum, edge_index, dist, emb, out, n_edges);
        return;
    }

    unsigned int* temb = (unsigned int*)d_ws;

    transpose_cast_kernel<<<N_PAIRS / TP_PAIRS, BLOCK_THREADS, 0, stream>>>(emb, temb);

    const int grid = (n_edges + BLOCK_THREADS - 1) / BLOCK_THREADS;
    // Two slice passes: each keeps a 4MB half-table L2-resident on every XCD.
    gather_kernel<<<grid, BLOCK_THREADS, 0, stream>>>(
        anum, edge_index, dist, (const unsigned short*)temb, out, n_edges,
        0, SLICE_P);
    gather_kernel<<<grid, BLOCK_THREADS, 0, stream>>>(
        anum, edge_index, dist, (const unsigned short*)temb, out, n_edges,
        SLICE_P, N_PAIRS);
}

// Round 5
// 125.402 us; speedup vs baseline: 1.0668x; 1.0668x over previous
//
#include <hip/hip_runtime.h>

// EfficientPairEmbed: out[0, e, h] = sum_g emb[anum[src_e], anum[dst_e], 0, h, g] * rbf[e, g]
// rbf[e,g] = exp(-0.5/std^2 * (dist_e - offset_g)^2), offsets = linspace(0, 12, 50), std = 12/50.
//
// R10: R7 (coalescing), R8 (aligned 1-line windows), R9 (L2 temporal slicing) were
// all null-to-negative => gather is NOT window-traffic bound. R9's +18.5us for one
// extra edge-scan pass shows the gather is a ~16-18us per-edge-scan latency/stream
// kernel; the other ~92us of the timed window is harness 256MB poison fills (the
// only dispatches >42us in rocprof). So: revert to the R6 structure (best measured)
// and close the last latency gap: 2 edges per thread -> int2/float2 metadata loads,
// 16 outstanding window loads per thread (2x MLP), 64B contiguous out stores.
// Numerically identical to R6 (same bf16 table, same windows): absmax 0.03125.

#define G_NUM 50
#define H_NUM 8
#define NE_NUM 100
#define N_PAIRS (NE_NUM * NE_NUM)
#define WIN 8
#define BLOCK_THREADS 256
#define TP_PAIRS 8                     // pairs per transpose block

#define SPACING (12.0f / (float)(G_NUM - 1))
#define INV_SPACING ((float)(G_NUM - 1) / 12.0f)
#define RBF_COEFF (-0.5f * ((float)G_NUM / 12.0f) * ((float)G_NUM / 12.0f))

typedef float vf4 __attribute__((ext_vector_type(4)));   // native vec for nontemporal stores

__device__ __forceinline__ float bf_lo(unsigned u) { return __uint_as_float(u << 16); }
__device__ __forceinline__ float bf_hi(unsigned u) { return __uint_as_float(u & 0xffff0000u); }

// ---------------- Pass 0: emb [p][h][g] fp32 -> temb [p][g][h] bf16, LDS-staged ----------------
__global__ __launch_bounds__(BLOCK_THREADS) void transpose_cast_kernel(
    const float* __restrict__ emb, unsigned int* __restrict__ temb)
{
    __shared__ float ls[TP_PAIRS * H_NUM * G_NUM];          // 3200 floats, 12.8 KB

    const int tid = threadIdx.x;
    const int p0  = blockIdx.x * TP_PAIRS;

    // Coalesced read: 800 float4 per block.
    const float4* src = (const float4*)(emb + (size_t)p0 * (H_NUM * G_NUM));
    #pragma unroll
    for (int i = tid; i < TP_PAIRS * H_NUM * G_NUM / 4; i += BLOCK_THREADS)
        ((float4*)ls)[i] = src[i];
    __syncthreads();

    // Coalesced write: 1600 packed-bf16 uints per block.
    unsigned int* dst = temb + (size_t)p0 * (H_NUM * G_NUM / 2);
    #pragma unroll
    for (int i = tid; i < TP_PAIRS * H_NUM * G_NUM / 2; i += BLOCK_THREADS) {
        int q  = i / (H_NUM * G_NUM / 2);          // local pair
        int u  = i - q * (H_NUM * G_NUM / 2);      // uint idx within pair: [g][h/2]
        int g  = u >> 2;
        int h0 = (u & 3) * 2;
        float f0 = ls[q * (H_NUM * G_NUM) + h0 * G_NUM + g];
        float f1 = ls[q * (H_NUM * G_NUM) + (h0 + 1) * G_NUM + g];
        unsigned u0 = __float_as_uint(f0);
        unsigned u1 = __float_as_uint(f1);
        unsigned b0 = (u0 + 0x7fffu + ((u0 >> 16) & 1u)) >> 16;   // RNE bf16
        unsigned b1 = (u1 + 0x7fffu + ((u1 >> 16) & 1u)) >> 16;
        dst[i] = (b1 << 16) | (b0 & 0xffffu);
    }
}

// ---------------- Pass 1: windowed gather, 2 edges/thread (2x MLP) ----------------
__global__ __launch_bounds__(BLOCK_THREADS) void gather_kernel(
    const int* __restrict__ anum,
    const int* __restrict__ edge_index,
    const float* __restrict__ dist,
    const unsigned short* __restrict__ temb,
    float* __restrict__ out,
    int n_edges)
{
    const int t  = blockIdx.x * BLOCK_THREADS + threadIdx.x;
    const int e0 = 2 * t;
    if (e0 >= n_edges) return;
    const int e1 = (e0 + 1 < n_edges) ? (e0 + 1) : e0;

    // ---- metadata: vector loads, nontemporal (streams must not evict the table) ----
    int  s0, s1, d0, d1;
    float dva, dvb;
    {
        // edge_index rows are contiguous: [0][*]=src, [1][*]=dst
        int2 sv = *(const int2*)(edge_index + e0);            // src e0, e0+1
        int2 dv2 = *(const int2*)(edge_index + n_edges + e0); // dst e0, e0+1
        float2 fv = *(const float2*)(dist + e0);
        s0 = sv.x; s1 = (e1 != e0) ? sv.y : sv.x;
        d0 = dv2.x; d1 = (e1 != e0) ? dv2.y : dv2.x;
        dva = fv.x; dvb = (e1 != e0) ? fv.y : fv.x;
    }

    // anum: 4 random 4B loads from a 200KB (L2-resident) table
    const int pA = anum[s0] * NE_NUM + anum[d0];
    const int pB = anum[s1] * NE_NUM + anum[d1];

    int gA = (int)(dva * INV_SPACING) - 3;
    gA = gA < 0 ? 0 : (gA > G_NUM - WIN ? G_NUM - WIN : gA);
    int gB = (int)(dvb * INV_SPACING) - 3;
    gB = gB < 0 ? 0 : (gB > G_NUM - WIN ? G_NUM - WIN : gB);

    const unsigned short* wA = temb + (size_t)pA * (H_NUM * G_NUM) + gA * H_NUM;
    const unsigned short* wB = temb + (size_t)pB * (H_NUM * G_NUM) + gB * H_NUM;

    // ---- phase A: issue all 16 independent 16B loads (two chains interleaved) ----
    uint4 vA[WIN], vB[WIN];
    #pragma unroll
    for (int r = 0; r < WIN; ++r) {
        vA[r] = *(const uint4*)(wA + r * H_NUM);
        vB[r] = *(const uint4*)(wB + r * H_NUM);
    }

    // ---- phase B: rbf weight + accumulate, both edges ----
    float aA[H_NUM] = {0,0,0,0,0,0,0,0};
    float aB[H_NUM] = {0,0,0,0,0,0,0,0};
    #pragma unroll
    for (int r = 0; r < WIN; ++r) {
        float dfA = dva - (float)(gA + r) * SPACING;
        float rbA = __expf(RBF_COEFF * dfA * dfA);
        aA[0] += rbA * bf_lo(vA[r].x);  aA[1] += rbA * bf_hi(vA[r].x);
        aA[2] += rbA * bf_lo(vA[r].y);  aA[3] += rbA * bf_hi(vA[r].y);
        aA[4] += rbA * bf_lo(vA[r].z);  aA[5] += rbA * bf_hi(vA[r].z);
        aA[6] += rbA * bf_lo(vA[r].w);  aA[7] += rbA * bf_hi(vA[r].w);

        float dfB = dvb - (float)(gB + r) * SPACING;
        float rbB = __expf(RBF_COEFF * dfB * dfB);
        aB[0] += rbB * bf_lo(vB[r].x);  aB[1] += rbB * bf_hi(vB[r].x);
        aB[2] += rbB * bf_lo(vB[r].y);  aB[3] += rbB * bf_hi(vB[r].y);
        aB[4] += rbB * bf_lo(vB[r].z);  aB[5] += rbB * bf_hi(vB[r].z);
        aB[6] += rbB * bf_lo(vB[r].w);  aB[7] += rbB * bf_hi(vB[r].w);
    }

    // ---- store: 64B contiguous per thread, nontemporal ----
    float* ob = out + (size_t)e0 * H_NUM;
    vf4 p0 = {aA[0], aA[1], aA[2], aA[3]};
    vf4 p1 = {aA[4], aA[5], aA[6], aA[7]};
    __builtin_nontemporal_store(p0, (vf4*)ob);
    __builtin_nontemporal_store(p1, (vf4*)(ob + 4));
    if (e1 != e0) {
        vf4 p2 = {aB[0], aB[1], aB[2], aB[3]};
        vf4 p3 = {aB[4], aB[5], aB[6], aB[7]};
        __builtin_nontemporal_store(p2, (vf4*)(ob + 8));
        __builtin_nontemporal_store(p3, (vf4*)(ob + 12));
    }
}

// ---------------- Fallback (ws-free): exact fp32 direct kernel ----------------
__global__ __launch_bounds__(BLOCK_THREADS) void direct_kernel(
    const int* __restrict__ anum,
    const int* __restrict__ edge_index,
    const float* __restrict__ dist,
    const float* __restrict__ emb,
    float* __restrict__ out,
    int n_edges)
{
    __shared__ int   pair_s[32];
    __shared__ float dist_sd[32];
    __shared__ float rbf_sd[32 * G_NUM];

    const int tid = threadIdx.x;
    const int e0  = blockIdx.x * 32;

    if (tid < 32) {
        int e = e0 + tid;
        if (e >= n_edges) e = n_edges - 1;
        int s  = edge_index[e];
        int d  = edge_index[n_edges + e];
        pair_s[tid] = (anum[s] * NE_NUM + anum[d]) * (H_NUM * G_NUM);
        dist_sd[tid] = dist[e];
    }
    __syncthreads();

    for (int idx = tid; idx < 32 * G_NUM; idx += BLOCK_THREADS) {
        int el = idx / G_NUM;
        int g  = idx - el * G_NUM;
        float diff = dist_sd[el] - (float)g * SPACING;
        rbf_sd[idx] = __expf(RBF_COEFF * diff * diff);
    }
    __syncthreads();

    const int el = tid >> 3;
    const int h  = tid & 7;
    const float* ebase = emb + pair_s[el] + h * G_NUM;
    const float* rbase = rbf_sd + el * G_NUM;

    float acc = 0.0f;
    #pragma unroll
    for (int g2 = 0; g2 < G_NUM / 2; ++g2) {
        float2 ev = *(const float2*)(ebase + 2 * g2);
        float2 rv = *(const float2*)(rbase + 2 * g2);
        acc += ev.x * rv.x + ev.y * rv.y;
    }

    if (e0 + el < n_edges)
        out[e0 * H_NUM + tid] = acc;
}

extern "C" void kernel_launch(void* const* d_in, const int* in_sizes, int n_in,
                              void* d_out, int out_size, void* d_ws, size_t ws_size,
                              hipStream_t stream) {
    const int*   anum       = (const int*)d_in[0];
    const int*   edge_index = (const int*)d_in[1];
    const float* dist       = (const float*)d_in[2];
    const float* emb        = (const float*)d_in[3];
    float*       out        = (float*)d_out;
    const int n_edges = in_sizes[2];

    const size_t temb_bytes = (size_t)N_PAIRS * H_NUM * G_NUM * sizeof(unsigned short); // 8 MB

    if (ws_size < temb_bytes) {
        const int grid = (n_edges + 31) / 32;
        direct_kernel<<<grid, BLOCK_THREADS, 0, stream>>>(
            anum, edge_index, dist, emb, out, n_edges);
        return;
    }

    unsigned int* temb = (unsigned int*)d_ws;

    transpose_cast_kernel<<<N_PAIRS / TP_PAIRS, BLOCK_THREADS, 0, stream>>>(emb, temb);

    const int n_half = (n_edges + 1) / 2;
    const int grid = (n_half + BLOCK_THREADS - 1) / BLOCK_THREADS;
    gather_kernel<<<grid, BLOCK_THREADS, 0, stream>>>(
        anum, edge_index, dist, (const unsigned short*)temb, out, n_edges);
}